// Round 1
// baseline (476.730 us; speedup 1.0000x reference)
//
#include <hip/hip_runtime.h>

// ---------------------------------------------------------------------------
// SelfAttentionLayer: out[b,s,c*16+h] = softmax_k( (q.k)/32 masked ) @ v
//   q/k/v[c,b,s,h] = (X @ W{q,k,v}^T)[b,s,c*16+h]
// X: [32,256,1024] f32, mask: [32,256] f32, W*: [1024,1024] f32 (row=[out])
// Strategy: cast to bf16, one MFMA GEMM X[8192,1024] @ W[3072,1024]^T -> QKV
// bf16 [8192,3072], then per-(head,batch) VALU flash attention.
// ---------------------------------------------------------------------------

typedef unsigned short u16;
typedef unsigned int u32;
typedef __attribute__((ext_vector_type(8))) short short8;
typedef __attribute__((ext_vector_type(4))) float floatx4;

__device__ __forceinline__ u16 f2bf(float f) {
  union { float f; u32 u; } x; x.f = f;
  u32 r = x.u + 0x7fffu + ((x.u >> 16) & 1u);  // RNE
  return (u16)(r >> 16);
}
__device__ __forceinline__ float bf2f(u16 u) {
  union { u32 u; float f; } x; x.u = ((u32)u) << 16;
  return x.f;
}

// ---------------------------------------------------------------------------
// Cast f32 -> bf16, 4 elems/thread, exact-size grids (n % 1024 == 0)
// ---------------------------------------------------------------------------
__global__ __launch_bounds__(256) void cast_f32_bf16(const float* __restrict__ in,
                                                     u16* __restrict__ out) {
  int i = (blockIdx.x * 256 + threadIdx.x) * 4;
  float4 v = *(const float4*)(in + i);
  u32 lo = (u32)f2bf(v.x) | ((u32)f2bf(v.y) << 16);
  u32 hi = (u32)f2bf(v.z) | ((u32)f2bf(v.w) << 16);
  uint2 o; o.x = lo; o.y = hi;
  *(uint2*)(out + i) = o;
}

// ---------------------------------------------------------------------------
// GEMM: C[m][n] = sum_k A[m][k] * B[n][k]; A=[8192,1024], B=[3072,1024] bf16.
// 128x128 tile, BK=64, 4 waves each computing 64x64 via 4x4 mfma 16x16x32.
// LDS row stride 72 elems (144 B) -> even 8-dword/bank distribution.
// ---------------------------------------------------------------------------
#define GM 8192
#define GN 3072
#define GK 1024
#define LDSS 72

__global__ __launch_bounds__(256) void gemm_qkv(const u16* __restrict__ A,
                                                const u16* __restrict__ B,
                                                u16* __restrict__ C) {
  __shared__ u16 As[128 * LDSS];
  __shared__ u16 Bs[128 * LDSS];

  const int t = threadIdx.x;
  const int m0 = blockIdx.y * 128;
  const int n0 = blockIdx.x * 128;
  const int wave = t >> 6;
  const int lane = t & 63;
  const int wm = (wave >> 1) * 64;
  const int wn = (wave & 1) * 64;
  const int lrow = lane & 15;          // fragment row/col within 16
  const int lk = (lane >> 4) * 8;      // fragment k offset (quad*8)

  // staging: thread t loads 16B at (row = t>>3 + i*32, col = (t&7)*8)
  const int srow = t >> 3;
  const int scol = (t & 7) * 8;

  floatx4 acc[4][4] = {};

  uint4 pa[4], pb[4];
#pragma unroll
  for (int i = 0; i < 4; i++) {
    pa[i] = *(const uint4*)(A + (size_t)(m0 + srow + i * 32) * GK + scol);
    pb[i] = *(const uint4*)(B + (size_t)(n0 + srow + i * 32) * GK + scol);
  }

  for (int k0 = 0; k0 < GK; k0 += 64) {
    __syncthreads();
#pragma unroll
    for (int i = 0; i < 4; i++) {
      *(uint4*)(As + (srow + i * 32) * LDSS + scol) = pa[i];
      *(uint4*)(Bs + (srow + i * 32) * LDSS + scol) = pb[i];
    }
    __syncthreads();
    if (k0 + 64 < GK) {
      const int kn = k0 + 64;
#pragma unroll
      for (int i = 0; i < 4; i++) {
        pa[i] = *(const uint4*)(A + (size_t)(m0 + srow + i * 32) * GK + kn + scol);
        pb[i] = *(const uint4*)(B + (size_t)(n0 + srow + i * 32) * GK + kn + scol);
      }
    }
#pragma unroll
    for (int kk = 0; kk < 2; kk++) {
      short8 af[4], bf[4];
#pragma unroll
      for (int i = 0; i < 4; i++)
        af[i] = *(const short8*)(As + (wm + i * 16 + lrow) * LDSS + kk * 32 + lk);
#pragma unroll
      for (int j = 0; j < 4; j++)
        bf[j] = *(const short8*)(Bs + (wn + j * 16 + lrow) * LDSS + kk * 32 + lk);
#pragma unroll
      for (int i = 0; i < 4; i++)
#pragma unroll
        for (int j = 0; j < 4; j++)
          acc[i][j] = __builtin_amdgcn_mfma_f32_16x16x32_bf16(af[i], bf[j], acc[i][j], 0, 0, 0);
    }
  }

  // epilogue: C/D layout col = lane&15, row = (lane>>4)*4 + r  [m89-verified]
  const int crow0 = (lane >> 4) * 4;
  const int ccol = lane & 15;
#pragma unroll
  for (int i = 0; i < 4; i++)
#pragma unroll
    for (int j = 0; j < 4; j++)
#pragma unroll
      for (int r = 0; r < 4; r++) {
        int grow = m0 + wm + i * 16 + crow0 + r;
        int gcol = n0 + wn + j * 16 + ccol;
        C[(size_t)grow * GN + gcol] = f2bf(acc[i][j][r]);
      }
}

// ---------------------------------------------------------------------------
// Attention: block = (head c, batch b); 256 threads; thread t owns q-row t.
// K,V rows staged fp32 in LDS (broadcast reads in inner loop).
// softmax without max-subtraction: logits = q.k/32, |logit| small, exp safe.
// All-masked row fallback -> uniform weights (matches jax softmax of -1e9).
// ---------------------------------------------------------------------------
__global__ __launch_bounds__(256) void attn_kernel(const u16* __restrict__ QKV,
                                                   const float* __restrict__ mask,
                                                   float* __restrict__ out) {
  __shared__ float k_s[256 * 16];
  __shared__ float v_s[256 * 16];
  __shared__ float m_s[256];

  const int c = blockIdx.x;   // 0..63
  const int b = blockIdx.y;   // 0..31
  const int t = threadIdx.x;  // q row

  const size_t rowbase = (size_t)(b * 256 + t) * GN;
  const u16* qp = QKV + rowbase + 0 * 1024 + c * 16;
  const u16* kp = QKV + rowbase + 1 * 1024 + c * 16;
  const u16* vp = QKV + rowbase + 2 * 1024 + c * 16;

  union { uint4 v; u16 s[8]; } bufa, bufb;

  float q[16];
  bufa.v = *(const uint4*)(qp);
  bufb.v = *(const uint4*)(qp + 8);
#pragma unroll
  for (int h = 0; h < 8; h++) { q[h] = bf2f(bufa.s[h]); q[h + 8] = bf2f(bufb.s[h]); }

  bufa.v = *(const uint4*)(kp);
  bufb.v = *(const uint4*)(kp + 8);
#pragma unroll
  for (int h = 0; h < 8; h++) {
    k_s[t * 16 + h] = bf2f(bufa.s[h]);
    k_s[t * 16 + 8 + h] = bf2f(bufb.s[h]);
  }
  bufa.v = *(const uint4*)(vp);
  bufb.v = *(const uint4*)(vp + 8);
#pragma unroll
  for (int h = 0; h < 8; h++) {
    v_s[t * 16 + h] = bf2f(bufa.s[h]);
    v_s[t * 16 + 8 + h] = bf2f(bufb.s[h]);
  }
  m_s[t] = mask[b * 256 + t];
  __syncthreads();

  const float mq = m_s[t];
  float l = 0.0f;
  float o[16];
#pragma unroll
  for (int h = 0; h < 16; h++) o[h] = 0.0f;

  for (int j = 0; j < 256; j++) {
    const float4 kr0 = *(const float4*)(k_s + j * 16);
    const float4 kr1 = *(const float4*)(k_s + j * 16 + 4);
    const float4 kr2 = *(const float4*)(k_s + j * 16 + 8);
    const float4 kr3 = *(const float4*)(k_s + j * 16 + 12);
    // 4 partial sums to break the FMA dependence chain
    float s0 = q[0] * kr0.x + q[4] * kr1.x;
    float s1 = q[1] * kr0.y + q[5] * kr1.y;
    float s2 = q[2] * kr0.z + q[6] * kr1.z;
    float s3 = q[3] * kr0.w + q[7] * kr1.w;
    s0 += q[8] * kr2.x + q[12] * kr3.x;
    s1 += q[9] * kr2.y + q[13] * kr3.y;
    s2 += q[10] * kr2.z + q[14] * kr3.z;
    s3 += q[11] * kr2.w + q[15] * kr3.w;
    float s = ((s0 + s1) + (s2 + s3)) * 0.03125f;  // / sqrt(1024)

    const bool valid = (mq * m_s[j]) > 0.0f;
    const float e = __expf(s);
    const float p = valid ? e : 0.0f;
    l += p;

    const float4 vr0 = *(const float4*)(v_s + j * 16);
    const float4 vr1 = *(const float4*)(v_s + j * 16 + 4);
    const float4 vr2 = *(const float4*)(v_s + j * 16 + 8);
    const float4 vr3 = *(const float4*)(v_s + j * 16 + 12);
    o[0] += p * vr0.x;  o[1] += p * vr0.y;  o[2] += p * vr0.z;  o[3] += p * vr0.w;
    o[4] += p * vr1.x;  o[5] += p * vr1.y;  o[6] += p * vr1.z;  o[7] += p * vr1.w;
    o[8] += p * vr2.x;  o[9] += p * vr2.y;  o[10] += p * vr2.z; o[11] += p * vr2.w;
    o[12] += p * vr3.x; o[13] += p * vr3.y; o[14] += p * vr3.z; o[15] += p * vr3.w;
  }

  float inv;
  if (l > 0.0f) {
    inv = 1.0f / l;
  } else {
    // all keys masked (or q masked): reference softmax -> uniform 1/256
#pragma unroll
    for (int h = 0; h < 16; h++) o[h] = 0.0f;
    for (int j = 0; j < 256; j++)
#pragma unroll
      for (int h = 0; h < 16; h++) o[h] += v_s[j * 16 + h];
    inv = 1.0f / 256.0f;
  }

  float* op = out + (size_t)(b * 256 + t) * 1024 + c * 16;
  float4 r;
  r.x = o[0] * inv; r.y = o[1] * inv; r.z = o[2] * inv; r.w = o[3] * inv;
  *(float4*)(op + 0) = r;
  r.x = o[4] * inv; r.y = o[5] * inv; r.z = o[6] * inv; r.w = o[7] * inv;
  *(float4*)(op + 4) = r;
  r.x = o[8] * inv; r.y = o[9] * inv; r.z = o[10] * inv; r.w = o[11] * inv;
  *(float4*)(op + 8) = r;
  r.x = o[12] * inv; r.y = o[13] * inv; r.z = o[14] * inv; r.w = o[15] * inv;
  *(float4*)(op + 12) = r;
}

// ---------------------------------------------------------------------------
// Launch
// ---------------------------------------------------------------------------
extern "C" void kernel_launch(void* const* d_in, const int* in_sizes, int n_in,
                              void* d_out, int out_size, void* d_ws, size_t ws_size,
                              hipStream_t stream) {
  const float* x    = (const float*)d_in[0];  // [32,256,1024]
  const float* mask = (const float*)d_in[1];  // [32,256]
  const float* Wq   = (const float*)d_in[2];  // [1024,1024]
  const float* Wk   = (const float*)d_in[3];
  const float* Wv   = (const float*)d_in[4];
  float* out = (float*)d_out;

  // workspace layout (bf16 = u16): XB 16MB, WB 6MB, QKV 50MB  (~73.4 MB)
  u16* XB  = (u16*)d_ws;                    // [8192][1024]
  u16* WB  = XB + (size_t)GM * GK;          // [3072][1024] (Wq,Wk,Wv stacked)
  u16* QKV = WB + (size_t)GN * GK;          // [8192][3072]

  cast_f32_bf16<<<8192, 256, 0, stream>>>(x, XB);                    // 8.39M elems
  cast_f32_bf16<<<1024, 256, 0, stream>>>(Wq, WB);                   // 1.05M each
  cast_f32_bf16<<<1024, 256, 0, stream>>>(Wk, WB + 1024 * 1024);
  cast_f32_bf16<<<1024, 256, 0, stream>>>(Wv, WB + 2 * 1024 * 1024);

  gemm_qkv<<<dim3(GN / 128, GM / 128), 256, 0, stream>>>(XB, WB, QKV);

  attn_kernel<<<dim3(64, 32), 256, 0, stream>>>(QKV, mask, out);
}

// Round 2
// 470.294 us; speedup vs baseline: 1.0137x; 1.0137x over previous
//
#include <hip/hip_runtime.h>

// ---------------------------------------------------------------------------
// SelfAttentionLayer: out[b,s,c*16+h] = softmax_k( (q.k)/32 masked ) @ v
// Strategy: cast to bf16; one MFMA GEMM X[8192,1024] @ W[3072,1024]^T with a
// permuted-coalesced epilogue writing QKV as [qkv][head c][b][s][h] bf16;
// then per-(head,batch) VALU flash attention with coalesced loads.
// ---------------------------------------------------------------------------

typedef unsigned short u16;
typedef unsigned int u32;
typedef __attribute__((ext_vector_type(8))) short short8;
typedef __attribute__((ext_vector_type(4))) float floatx4;

__device__ __forceinline__ u16 f2bf(float f) {
  union { float f; u32 u; } x; x.f = f;
  u32 r = x.u + 0x7fffu + ((x.u >> 16) & 1u);  // RNE
  return (u16)(r >> 16);
}
__device__ __forceinline__ float bf2f(u16 u) {
  union { u32 u; float f; } x; x.u = ((u32)u) << 16;
  return x.f;
}

// ---------------------------------------------------------------------------
// Cast f32 -> bf16, 4 elems/thread
// ---------------------------------------------------------------------------
__global__ __launch_bounds__(256) void cast_f32_bf16(const float* __restrict__ in,
                                                     u16* __restrict__ out) {
  int i = (blockIdx.x * 256 + threadIdx.x) * 4;
  float4 v = *(const float4*)(in + i);
  u32 lo = (u32)f2bf(v.x) | ((u32)f2bf(v.y) << 16);
  u32 hi = (u32)f2bf(v.z) | ((u32)f2bf(v.w) << 16);
  uint2 o; o.x = lo; o.y = hi;
  *(uint2*)(out + i) = o;
}

// ---------------------------------------------------------------------------
// GEMM: C[m][n] = sum_k A[m][k]*B[n][k]; A=[8192,1024], B=[3072,1024] bf16.
// 128x128 tile, BK=64, 4 waves x (64x64 via 4x4 mfma 16x16x32).
// Epilogue: C-tile -> LDS (bf16, stride 136) -> coalesced permuted write:
//   QKV[((qkv*64 + c)*32 + b)*4096 + s*16 + h]
// Tile spans one (qkv, b), heads c0..c0+7, s-range s0..s0+127.
// ---------------------------------------------------------------------------
#define GM 8192
#define GN 3072
#define GK 1024
#define LDSS 72
#define CSTR 136  // epilogue C-tile stride (u16): 272B, 16B-aligned rows

__global__ __launch_bounds__(256) void gemm_qkv(const u16* __restrict__ A,
                                                const u16* __restrict__ B,
                                                u16* __restrict__ QKV) {
  __shared__ u16 smem[2 * 128 * LDSS];  // 36 KB; epilogue aliases as C-tile
  u16* As = smem;
  u16* Bs = smem + 128 * LDSS;

  const int t = threadIdx.x;
  const int m0 = blockIdx.y * 128;
  const int n0 = blockIdx.x * 128;
  const int wave = t >> 6;
  const int lane = t & 63;
  const int wm = (wave >> 1) * 64;
  const int wn = (wave & 1) * 64;
  const int lrow = lane & 15;
  const int lk = (lane >> 4) * 8;

  const int srow = t >> 3;
  const int scol = (t & 7) * 8;

  floatx4 acc[4][4] = {};

  uint4 pa[4], pb[4];
#pragma unroll
  for (int i = 0; i < 4; i++) {
    pa[i] = *(const uint4*)(A + (size_t)(m0 + srow + i * 32) * GK + scol);
    pb[i] = *(const uint4*)(B + (size_t)(n0 + srow + i * 32) * GK + scol);
  }

  for (int k0 = 0; k0 < GK; k0 += 64) {
    __syncthreads();
#pragma unroll
    for (int i = 0; i < 4; i++) {
      *(uint4*)(As + (srow + i * 32) * LDSS + scol) = pa[i];
      *(uint4*)(Bs + (srow + i * 32) * LDSS + scol) = pb[i];
    }
    __syncthreads();
    if (k0 + 64 < GK) {
      const int kn = k0 + 64;
#pragma unroll
      for (int i = 0; i < 4; i++) {
        pa[i] = *(const uint4*)(A + (size_t)(m0 + srow + i * 32) * GK + kn + scol);
        pb[i] = *(const uint4*)(B + (size_t)(n0 + srow + i * 32) * GK + kn + scol);
      }
    }
#pragma unroll
    for (int kk = 0; kk < 2; kk++) {
      short8 af[4], bf[4];
#pragma unroll
      for (int i = 0; i < 4; i++)
        af[i] = *(const short8*)(As + (wm + i * 16 + lrow) * LDSS + kk * 32 + lk);
#pragma unroll
      for (int j = 0; j < 4; j++)
        bf[j] = *(const short8*)(Bs + (wn + j * 16 + lrow) * LDSS + kk * 32 + lk);
#pragma unroll
      for (int i = 0; i < 4; i++)
#pragma unroll
        for (int j = 0; j < 4; j++)
          acc[i][j] = __builtin_amdgcn_mfma_f32_16x16x32_bf16(af[i], bf[j], acc[i][j], 0, 0, 0);
    }
  }

  // ---- epilogue: acc -> LDS bf16 tile -> coalesced permuted global write ----
  __syncthreads();  // all ds_reads of As/Bs done before aliasing
  u16* Cs = smem;   // [128][CSTR]

  // C/D layout: col = lane&15, row = (lane>>4)*4 + r  [m89-verified]
  const int crow0 = (lane >> 4) * 4;
  const int ccol = lane & 15;
#pragma unroll
  for (int i = 0; i < 4; i++)
#pragma unroll
    for (int j = 0; j < 4; j++)
#pragma unroll
      for (int r = 0; r < 4; r++)
        Cs[(wm + i * 16 + crow0 + r) * CSTR + wn + j * 16 + ccol] = f2bf(acc[i][j][r]);
  __syncthreads();

  const int qkv = n0 >> 10;          // 0..2
  const int c0 = (n0 >> 4) & 63;     // first head in tile (8 heads/tile)
  const int b = m0 >> 8;             // batch
  const int s0 = m0 & 255;           // 0 or 128
  const int s = t >> 1;              // 0..127 (local s)
  const int hh = (t & 1) * 8;        // 0 or 8

#pragma unroll
  for (int g = 0; g < 8; g++) {
    uint4 val = *(const uint4*)(Cs + s * CSTR + g * 16 + hh);
    size_t base = (((size_t)(qkv * 64 + c0 + g) * 32 + b) * 256 + (s0 + s)) * 16 + hh;
    *(uint4*)(QKV + base) = val;
  }
}

// ---------------------------------------------------------------------------
// Attention: block = (head c, batch b); 256 threads; thread t owns q-row t.
// QKV layout [qkv][c][b][s][h] -> all loads fully coalesced.
// ---------------------------------------------------------------------------
#define QKVSEG (64 * 32 * 4096)  // elements per qkv segment

__global__ __launch_bounds__(256) void attn_kernel(const u16* __restrict__ QKV,
                                                   const float* __restrict__ mask,
                                                   float* __restrict__ out) {
  __shared__ float k_s[256 * 16];
  __shared__ float v_s[256 * 16];
  __shared__ float m_s[256];

  const int c = blockIdx.x;   // 0..63
  const int b = blockIdx.y;   // 0..31
  const int t = threadIdx.x;  // q row

  const size_t hb = ((size_t)c * 32 + b) * 4096 + t * 16;
  const u16* qp = QKV + hb;
  const u16* kp = QKV + QKVSEG + hb;
  const u16* vp = QKV + 2 * QKVSEG + hb;

  union { uint4 v; u16 s[8]; } bufa, bufb;

  float q[16];
  bufa.v = *(const uint4*)(qp);
  bufb.v = *(const uint4*)(qp + 8);
#pragma unroll
  for (int h = 0; h < 8; h++) { q[h] = bf2f(bufa.s[h]); q[h + 8] = bf2f(bufb.s[h]); }

  bufa.v = *(const uint4*)(kp);
  bufb.v = *(const uint4*)(kp + 8);
#pragma unroll
  for (int h = 0; h < 8; h++) {
    k_s[t * 16 + h] = bf2f(bufa.s[h]);
    k_s[t * 16 + 8 + h] = bf2f(bufb.s[h]);
  }
  bufa.v = *(const uint4*)(vp);
  bufb.v = *(const uint4*)(vp + 8);
#pragma unroll
  for (int h = 0; h < 8; h++) {
    v_s[t * 16 + h] = bf2f(bufa.s[h]);
    v_s[t * 16 + 8 + h] = bf2f(bufb.s[h]);
  }
  m_s[t] = mask[b * 256 + t];
  __syncthreads();

  const float mq = m_s[t];
  float l = 0.0f;
  float o[16];
#pragma unroll
  for (int h = 0; h < 16; h++) o[h] = 0.0f;

#pragma unroll 2
  for (int j = 0; j < 256; j++) {
    const float4 kr0 = *(const float4*)(k_s + j * 16);
    const float4 kr1 = *(const float4*)(k_s + j * 16 + 4);
    const float4 kr2 = *(const float4*)(k_s + j * 16 + 8);
    const float4 kr3 = *(const float4*)(k_s + j * 16 + 12);
    float s0 = q[0] * kr0.x + q[4] * kr1.x;
    float s1 = q[1] * kr0.y + q[5] * kr1.y;
    float s2 = q[2] * kr0.z + q[6] * kr1.z;
    float s3 = q[3] * kr0.w + q[7] * kr1.w;
    s0 += q[8] * kr2.x + q[12] * kr3.x;
    s1 += q[9] * kr2.y + q[13] * kr3.y;
    s2 += q[10] * kr2.z + q[14] * kr3.z;
    s3 += q[11] * kr2.w + q[15] * kr3.w;
    float s = ((s0 + s1) + (s2 + s3)) * 0.03125f;  // / sqrt(1024)

    const bool valid = (mq * m_s[j]) > 0.0f;
    const float e = __expf(s);
    const float p = valid ? e : 0.0f;
    l += p;

    const float4 vr0 = *(const float4*)(v_s + j * 16);
    const float4 vr1 = *(const float4*)(v_s + j * 16 + 4);
    const float4 vr2 = *(const float4*)(v_s + j * 16 + 8);
    const float4 vr3 = *(const float4*)(v_s + j * 16 + 12);
    o[0] += p * vr0.x;  o[1] += p * vr0.y;  o[2] += p * vr0.z;  o[3] += p * vr0.w;
    o[4] += p * vr1.x;  o[5] += p * vr1.y;  o[6] += p * vr1.z;  o[7] += p * vr1.w;
    o[8] += p * vr2.x;  o[9] += p * vr2.y;  o[10] += p * vr2.z; o[11] += p * vr2.w;
    o[12] += p * vr3.x; o[13] += p * vr3.y; o[14] += p * vr3.z; o[15] += p * vr3.w;
  }

  float inv;
  if (l > 0.0f) {
    inv = 1.0f / l;
  } else {
    // all keys masked: reference softmax of uniform -1e9 -> uniform 1/256
#pragma unroll
    for (int h = 0; h < 16; h++) o[h] = 0.0f;
    for (int j = 0; j < 256; j++)
#pragma unroll
      for (int h = 0; h < 16; h++) o[h] += v_s[j * 16 + h];
    inv = 1.0f / 256.0f;
  }

  float* op = out + (size_t)(b * 256 + t) * 1024 + c * 16;
  float4 r;
  r.x = o[0] * inv; r.y = o[1] * inv; r.z = o[2] * inv; r.w = o[3] * inv;
  *(float4*)(op + 0) = r;
  r.x = o[4] * inv; r.y = o[5] * inv; r.z = o[6] * inv; r.w = o[7] * inv;
  *(float4*)(op + 4) = r;
  r.x = o[8] * inv; r.y = o[9] * inv; r.z = o[10] * inv; r.w = o[11] * inv;
  *(float4*)(op + 8) = r;
  r.x = o[12] * inv; r.y = o[13] * inv; r.z = o[14] * inv; r.w = o[15] * inv;
  *(float4*)(op + 12) = r;
}

// ---------------------------------------------------------------------------
// Launch
// ---------------------------------------------------------------------------
extern "C" void kernel_launch(void* const* d_in, const int* in_sizes, int n_in,
                              void* d_out, int out_size, void* d_ws, size_t ws_size,
                              hipStream_t stream) {
  const float* x    = (const float*)d_in[0];  // [32,256,1024]
  const float* mask = (const float*)d_in[1];  // [32,256]
  const float* Wq   = (const float*)d_in[2];  // [1024,1024]
  const float* Wk   = (const float*)d_in[3];
  const float* Wv   = (const float*)d_in[4];
  float* out = (float*)d_out;

  u16* XB  = (u16*)d_ws;                    // [8192][1024] bf16
  u16* WB  = XB + (size_t)GM * GK;          // [3072][1024] (Wq,Wk,Wv stacked)
  u16* QKV = WB + (size_t)GN * GK;          // permuted [3][64][32][256][16]

  cast_f32_bf16<<<8192, 256, 0, stream>>>(x, XB);
  cast_f32_bf16<<<1024, 256, 0, stream>>>(Wq, WB);
  cast_f32_bf16<<<1024, 256, 0, stream>>>(Wk, WB + 1024 * 1024);
  cast_f32_bf16<<<1024, 256, 0, stream>>>(Wv, WB + 2 * 1024 * 1024);

  gemm_qkv<<<dim3(GN / 128, GM / 128), 256, 0, stream>>>(XB, WB, QKV);

  attn_kernel<<<dim3(64, 32), 256, 0, stream>>>(QKV, mask, out);
}

// Round 3
// 298.173 us; speedup vs baseline: 1.5988x; 1.5773x over previous
//
#include <hip/hip_runtime.h>

// ---------------------------------------------------------------------------
// SelfAttentionLayer: out[b,s,c*16+h] = softmax_k( (q.k)/32 masked ) @ v
// R2: GEMM rebuilt on the m97 recipe: XCD-aware swizzle (A-strip resident in
// each XCD's L2), global_load_lds width-16 staging, XOR-swizzled stride-64
// LDS. Epilogue writes QKV permuted [qkv][head][b][s][h] (coalesced).
// Attention unchanged (next round: MFMA rewrite).
// ---------------------------------------------------------------------------

typedef unsigned short u16;
typedef unsigned int u32;
typedef __attribute__((ext_vector_type(8))) short short8;
typedef __attribute__((ext_vector_type(4))) float floatx4;

__device__ __forceinline__ u16 f2bf(float f) {
  union { float f; u32 u; } x; x.f = f;
  u32 r = x.u + 0x7fffu + ((x.u >> 16) & 1u);  // RNE
  return (u16)(r >> 16);
}
__device__ __forceinline__ float bf2f(u16 u) {
  union { u32 u; float f; } x; x.u = ((u32)u) << 16;
  return x.f;
}

// async global->LDS, 16B per lane; LDS dest = wave-uniform base + lane*16
__device__ __forceinline__ void gload16(const void* g, void* l) {
  typedef __attribute__((address_space(1))) const unsigned int gq;
  typedef __attribute__((address_space(3))) unsigned int lq;
  __builtin_amdgcn_global_load_lds((gq*)(size_t)g, (lq*)(size_t)l, 16, 0, 0);
}

// ---------------------------------------------------------------------------
// Cast f32 -> bf16, 4 elems/thread
// ---------------------------------------------------------------------------
__global__ __launch_bounds__(256) void cast_f32_bf16(const float* __restrict__ in,
                                                     u16* __restrict__ out) {
  int i = (blockIdx.x * 256 + threadIdx.x) * 4;
  float4 v = *(const float4*)(in + i);
  u32 lo = (u32)f2bf(v.x) | ((u32)f2bf(v.y) << 16);
  u32 hi = (u32)f2bf(v.z) | ((u32)f2bf(v.w) << 16);
  uint2 o; o.x = lo; o.y = hi;
  *(uint2*)(out + i) = o;
}

// ---------------------------------------------------------------------------
// GEMM: C[m][n] = sum_k A[m][k]*B[n][k]; A=[8192,1024], B=[3072,1024] bf16.
// 128x128 tile, BK=64, 4 waves x (64x64 via 4x4 mfma 16x16x32).
// LDS: unpadded stride 64 (global_load_lds-compatible), col-block XOR row&7
// swizzle -> fragment ds_read_b128 spreads 32 banks, 2 lanes/bank (free).
// Block swizzle: xcd = lid&7 owns m-tiles [8*xcd,8*xcd+8) (2MB A-strip in its
// L2), sweeps n-tiles; 8 consecutive blocks share one B-tile.
// Epilogue: C-tile -> LDS -> coalesced permuted write QKV[qkv][c][b][s][h].
// ---------------------------------------------------------------------------
#define GM 8192
#define GN 3072
#define GK 1024
#define CSTR 136  // epilogue C-tile stride (u16)

__global__ __launch_bounds__(256) void gemm_qkv(const u16* __restrict__ A,
                                                const u16* __restrict__ B,
                                                u16* __restrict__ QKV) {
  __shared__ u16 smem[17408];  // staging: 2*128*64 = 16384; epilogue: 128*136
  u16* As = smem;
  u16* Bs = smem + 128 * 64;

  const int t = threadIdx.x;
  const int lid = blockIdx.x;
  const int xcd = lid & 7;
  const int slot = lid >> 3;                 // 0..191
  const int m0 = (xcd * 8 + (slot & 7)) * 128;
  const int n0 = (slot >> 3) * 128;

  const int wave = t >> 6;
  const int lane = t & 63;
  const int wm = (wave >> 1) * 64;
  const int wn = (wave & 1) * 64;
  const int lrow = lane & 15;
  const int quad = lane >> 4;

  // staging geometry: one gload16 instr = 8 rows x 64 cols (1 KB)
  const int r_loc = lane >> 3;               // 0..7 row within group
  const int xb = (lane & 7) ^ r_loc;         // XOR-swizzled source col-block

  floatx4 acc[4][4] = {};

  const size_t arow = (size_t)(m0 + wave * 32 + r_loc) * GK + xb * 8;
  const size_t brow = (size_t)(n0 + wave * 32 + r_loc) * GK + xb * 8;

  for (int k0 = 0; k0 < GK; k0 += 64) {
    __syncthreads();  // prev iter's ds_reads done before DMA overwrites
#pragma unroll
    for (int i = 0; i < 4; i++) {
      gload16(A + arow + (size_t)i * 8 * GK + k0, As + (wave * 32 + i * 8) * 64);
      gload16(B + brow + (size_t)i * 8 * GK + k0, Bs + (wave * 32 + i * 8) * 64);
    }
    __syncthreads();  // drains vmcnt: LDS tile ready
#pragma unroll
    for (int kk = 0; kk < 2; kk++) {
      short8 af[4], bf[4];
#pragma unroll
      for (int i = 0; i < 4; i++) {
        int row = wm + i * 16 + lrow;
        int pos = ((kk * 4 + quad) ^ (lane & 7)) * 8;
        af[i] = *(const short8*)(As + row * 64 + pos);
      }
#pragma unroll
      for (int j = 0; j < 4; j++) {
        int row = wn + j * 16 + lrow;
        int pos = ((kk * 4 + quad) ^ (lane & 7)) * 8;
        bf[j] = *(const short8*)(Bs + row * 64 + pos);
      }
#pragma unroll
      for (int i = 0; i < 4; i++)
#pragma unroll
        for (int j = 0; j < 4; j++)
          acc[i][j] = __builtin_amdgcn_mfma_f32_16x16x32_bf16(af[i], bf[j], acc[i][j], 0, 0, 0);
    }
  }

  // ---- epilogue: acc -> LDS bf16 tile -> coalesced permuted global write ----
  __syncthreads();
  u16* Cs = smem;  // [128][CSTR]

  // C/D layout: col = lane&15, row = (lane>>4)*4 + r  [m89-verified]
  const int crow0 = quad * 4;
  const int ccol = lane & 15;
#pragma unroll
  for (int i = 0; i < 4; i++)
#pragma unroll
    for (int j = 0; j < 4; j++)
#pragma unroll
      for (int r = 0; r < 4; r++)
        Cs[(wm + i * 16 + crow0 + r) * CSTR + wn + j * 16 + ccol] = f2bf(acc[i][j][r]);
  __syncthreads();

  const int qkv = n0 >> 10;          // 0..2
  const int c0 = (n0 >> 4) & 63;     // first head in tile (8 heads/tile)
  const int b = m0 >> 8;             // batch
  const int s0 = m0 & 255;           // 0 or 128
  const int s = t >> 1;              // local s 0..127
  const int hh = (t & 1) * 8;

#pragma unroll
  for (int g = 0; g < 8; g++) {
    uint4 val = *(const uint4*)(Cs + s * CSTR + g * 16 + hh);
    size_t base = (((size_t)(qkv * 64 + c0 + g) * 32 + b) * 256 + (s0 + s)) * 16 + hh;
    *(uint4*)(QKV + base) = val;
  }
}

// ---------------------------------------------------------------------------
// Attention: block = (head c, batch b); 256 threads; thread t owns q-row t.
// QKV layout [qkv][c][b][s][h] -> all loads fully coalesced.
// ---------------------------------------------------------------------------
#define QKVSEG (64 * 32 * 4096)

__global__ __launch_bounds__(256) void attn_kernel(const u16* __restrict__ QKV,
                                                   const float* __restrict__ mask,
                                                   float* __restrict__ out) {
  __shared__ float k_s[256 * 16];
  __shared__ float v_s[256 * 16];
  __shared__ float m_s[256];

  const int c = blockIdx.x;
  const int b = blockIdx.y;
  const int t = threadIdx.x;

  const size_t hb = ((size_t)c * 32 + b) * 4096 + t * 16;
  const u16* qp = QKV + hb;
  const u16* kp = QKV + QKVSEG + hb;
  const u16* vp = QKV + 2 * QKVSEG + hb;

  union { uint4 v; u16 s[8]; } bufa, bufb;

  float q[16];
  bufa.v = *(const uint4*)(qp);
  bufb.v = *(const uint4*)(qp + 8);
#pragma unroll
  for (int h = 0; h < 8; h++) { q[h] = bf2f(bufa.s[h]); q[h + 8] = bf2f(bufb.s[h]); }

  bufa.v = *(const uint4*)(kp);
  bufb.v = *(const uint4*)(kp + 8);
#pragma unroll
  for (int h = 0; h < 8; h++) {
    k_s[t * 16 + h] = bf2f(bufa.s[h]);
    k_s[t * 16 + 8 + h] = bf2f(bufb.s[h]);
  }
  bufa.v = *(const uint4*)(vp);
  bufb.v = *(const uint4*)(vp + 8);
#pragma unroll
  for (int h = 0; h < 8; h++) {
    v_s[t * 16 + h] = bf2f(bufa.s[h]);
    v_s[t * 16 + 8 + h] = bf2f(bufb.s[h]);
  }
  m_s[t] = mask[b * 256 + t];
  __syncthreads();

  const float mq = m_s[t];
  float l = 0.0f;
  float o[16];
#pragma unroll
  for (int h = 0; h < 16; h++) o[h] = 0.0f;

#pragma unroll 2
  for (int j = 0; j < 256; j++) {
    const float4 kr0 = *(const float4*)(k_s + j * 16);
    const float4 kr1 = *(const float4*)(k_s + j * 16 + 4);
    const float4 kr2 = *(const float4*)(k_s + j * 16 + 8);
    const float4 kr3 = *(const float4*)(k_s + j * 16 + 12);
    float s0 = q[0] * kr0.x + q[4] * kr1.x;
    float s1 = q[1] * kr0.y + q[5] * kr1.y;
    float s2 = q[2] * kr0.z + q[6] * kr1.z;
    float s3 = q[3] * kr0.w + q[7] * kr1.w;
    s0 += q[8] * kr2.x + q[12] * kr3.x;
    s1 += q[9] * kr2.y + q[13] * kr3.y;
    s2 += q[10] * kr2.z + q[14] * kr3.z;
    s3 += q[11] * kr2.w + q[15] * kr3.w;
    float s = ((s0 + s1) + (s2 + s3)) * 0.03125f;  // / sqrt(1024)

    const bool valid = (mq * m_s[j]) > 0.0f;
    const float e = __expf(s);
    const float p = valid ? e : 0.0f;
    l += p;

    const float4 vr0 = *(const float4*)(v_s + j * 16);
    const float4 vr1 = *(const float4*)(v_s + j * 16 + 4);
    const float4 vr2 = *(const float4*)(v_s + j * 16 + 8);
    const float4 vr3 = *(const float4*)(v_s + j * 16 + 12);
    o[0] += p * vr0.x;  o[1] += p * vr0.y;  o[2] += p * vr0.z;  o[3] += p * vr0.w;
    o[4] += p * vr1.x;  o[5] += p * vr1.y;  o[6] += p * vr1.z;  o[7] += p * vr1.w;
    o[8] += p * vr2.x;  o[9] += p * vr2.y;  o[10] += p * vr2.z; o[11] += p * vr2.w;
    o[12] += p * vr3.x; o[13] += p * vr3.y; o[14] += p * vr3.z; o[15] += p * vr3.w;
  }

  float inv;
  if (l > 0.0f) {
    inv = 1.0f / l;
  } else {
    // all keys masked: reference softmax of uniform -1e9 -> uniform 1/256
#pragma unroll
    for (int h = 0; h < 16; h++) o[h] = 0.0f;
    for (int j = 0; j < 256; j++)
#pragma unroll
      for (int h = 0; h < 16; h++) o[h] += v_s[j * 16 + h];
    inv = 1.0f / 256.0f;
  }

  float* op = out + (size_t)(b * 256 + t) * 1024 + c * 16;
  float4 r;
  r.x = o[0] * inv; r.y = o[1] * inv; r.z = o[2] * inv; r.w = o[3] * inv;
  *(float4*)(op + 0) = r;
  r.x = o[4] * inv; r.y = o[5] * inv; r.z = o[6] * inv; r.w = o[7] * inv;
  *(float4*)(op + 4) = r;
  r.x = o[8] * inv; r.y = o[9] * inv; r.z = o[10] * inv; r.w = o[11] * inv;
  *(float4*)(op + 8) = r;
  r.x = o[12] * inv; r.y = o[13] * inv; r.z = o[14] * inv; r.w = o[15] * inv;
  *(float4*)(op + 12) = r;
}

// ---------------------------------------------------------------------------
// Launch
// ---------------------------------------------------------------------------
extern "C" void kernel_launch(void* const* d_in, const int* in_sizes, int n_in,
                              void* d_out, int out_size, void* d_ws, size_t ws_size,
                              hipStream_t stream) {
  const float* x    = (const float*)d_in[0];  // [32,256,1024]
  const float* mask = (const float*)d_in[1];  // [32,256]
  const float* Wq   = (const float*)d_in[2];  // [1024,1024]
  const float* Wk   = (const float*)d_in[3];
  const float* Wv   = (const float*)d_in[4];
  float* out = (float*)d_out;

  u16* XB  = (u16*)d_ws;                    // [8192][1024] bf16
  u16* WB  = XB + (size_t)GM * GK;          // [3072][1024] (Wq,Wk,Wv stacked)
  u16* QKV = WB + (size_t)GN * GK;          // permuted [3][64][32][256][16]

  cast_f32_bf16<<<8192, 256, 0, stream>>>(x, XB);
  cast_f32_bf16<<<1024, 256, 0, stream>>>(Wq, WB);
  cast_f32_bf16<<<1024, 256, 0, stream>>>(Wk, WB + 1024 * 1024);
  cast_f32_bf16<<<1024, 256, 0, stream>>>(Wv, WB + 2 * 1024 * 1024);

  gemm_qkv<<<1536, 256, 0, stream>>>(XB, WB, QKV);

  attn_kernel<<<dim3(64, 32), 256, 0, stream>>>(QKV, mask, out);
}

// Round 4
// 201.286 us; speedup vs baseline: 2.3684x; 1.4813x over previous
//
#include <hip/hip_runtime.h>

// ---------------------------------------------------------------------------
// SelfAttentionLayer: out[b,s,c*16+h] = softmax_k( (q.k)/32 masked ) @ v
// R3: attention rewritten on MFMA 16x16x16 bf16.
//   Trick: compute S^T = K·Q^T; its C/D fragment layout (row=quad*4+r,
//   col=lane&15) equals the B-operand layout (k=quad*4+i, n=lane&15), so
//   P^T = exp(S^T) feeds O^T = V^T·P^T with a lane-local transform only.
// GEMM (m97 recipe + XCD swizzle) unchanged; casts merged into one launch.
// ---------------------------------------------------------------------------

typedef unsigned short u16;
typedef unsigned int u32;
typedef __attribute__((ext_vector_type(8))) short short8;
typedef __attribute__((ext_vector_type(4))) short short4v;
typedef __attribute__((ext_vector_type(4))) float floatx4;

#if __has_builtin(__builtin_amdgcn_mfma_f32_16x16x16bf16_1k)
#define MFMA16(A, B, C) __builtin_amdgcn_mfma_f32_16x16x16bf16_1k(A, B, C, 0, 0, 0)
#elif __has_builtin(__builtin_amdgcn_mfma_f32_16x16x16_bf16)
#define MFMA16(A, B, C) __builtin_amdgcn_mfma_f32_16x16x16_bf16(A, B, C, 0, 0, 0)
#else
__device__ __forceinline__ floatx4 mfma16_asm(short4v a, short4v b, floatx4 c) {
  floatx4 d;
  asm volatile("v_mfma_f32_16x16x16_bf16 %0, %1, %2, %3"
               : "=v"(d) : "v"(a), "v"(b), "v"(c));
  return d;
}
#define MFMA16(A, B, C) mfma16_asm(A, B, C)
#endif

__device__ __forceinline__ u16 f2bf(float f) {
  union { float f; u32 u; } x; x.f = f;
  u32 r = x.u + 0x7fffu + ((x.u >> 16) & 1u);  // RNE
  return (u16)(r >> 16);
}
__device__ __forceinline__ float bf2f(u16 u) {
  union { u32 u; float f; } x; x.u = ((u32)u) << 16;
  return x.f;
}

// async global->LDS, 16B per lane; LDS dest = wave-uniform base + lane*16
__device__ __forceinline__ void gload16(const void* g, void* l) {
  typedef __attribute__((address_space(1))) const unsigned int gq;
  typedef __attribute__((address_space(3))) unsigned int lq;
  __builtin_amdgcn_global_load_lds((gq*)(size_t)g, (lq*)(size_t)l, 16, 0, 0);
}

#define GM 8192
#define GN 3072
#define GK 1024
#define CSTR 136
#define QKVSEG (64 * 32 * 4096)

// ---------------------------------------------------------------------------
// Merged cast f32 -> bf16: X (8192 blocks), Wq/Wk/Wv (1024 blocks each)
// ---------------------------------------------------------------------------
__global__ __launch_bounds__(256) void cast_all(const float* __restrict__ x,
                                                const float* __restrict__ wq,
                                                const float* __restrict__ wk,
                                                const float* __restrict__ wv,
                                                u16* __restrict__ XB,
                                                u16* __restrict__ WB) {
  int bid = blockIdx.x;
  const float* src; u16* dst; int off;
  if (bid < 8192)       { src = x;  dst = XB;                 off = bid; }
  else if (bid < 9216)  { src = wq; dst = WB;                 off = bid - 8192; }
  else if (bid < 10240) { src = wk; dst = WB + 1024 * 1024;   off = bid - 9216; }
  else                  { src = wv; dst = WB + 2 * 1024 * 1024; off = bid - 10240; }
  int i = (off * 256 + threadIdx.x) * 4;
  float4 v = *(const float4*)(src + i);
  u32 lo = (u32)f2bf(v.x) | ((u32)f2bf(v.y) << 16);
  u32 hi = (u32)f2bf(v.z) | ((u32)f2bf(v.w) << 16);
  uint2 o; o.x = lo; o.y = hi;
  *(uint2*)(dst + i) = o;
}

// ---------------------------------------------------------------------------
// GEMM: C[m][n] = sum_k A[m][k]*B[n][k]; 128x128 tile, BK=64, XCD swizzle,
// global_load_lds width-16, XOR-swizzled stride-64 LDS.
// Epilogue -> permuted coalesced QKV[qkv][c][b][s][h].
// ---------------------------------------------------------------------------
__global__ __launch_bounds__(256) void gemm_qkv(const u16* __restrict__ A,
                                                const u16* __restrict__ B,
                                                u16* __restrict__ QKV) {
  __shared__ u16 smem[17408];
  u16* As = smem;
  u16* Bs = smem + 128 * 64;

  const int t = threadIdx.x;
  const int lid = blockIdx.x;
  const int xcd = lid & 7;
  const int slot = lid >> 3;
  const int m0 = (xcd * 8 + (slot & 7)) * 128;
  const int n0 = (slot >> 3) * 128;

  const int wave = t >> 6;
  const int lane = t & 63;
  const int wm = (wave >> 1) * 64;
  const int wn = (wave & 1) * 64;
  const int lrow = lane & 15;
  const int quad = lane >> 4;

  const int r_loc = lane >> 3;
  const int xb = (lane & 7) ^ r_loc;

  floatx4 acc[4][4] = {};

  const size_t arow = (size_t)(m0 + wave * 32 + r_loc) * GK + xb * 8;
  const size_t brow = (size_t)(n0 + wave * 32 + r_loc) * GK + xb * 8;

  for (int k0 = 0; k0 < GK; k0 += 64) {
    __syncthreads();
#pragma unroll
    for (int i = 0; i < 4; i++) {
      gload16(A + arow + (size_t)i * 8 * GK + k0, As + (wave * 32 + i * 8) * 64);
      gload16(B + brow + (size_t)i * 8 * GK + k0, Bs + (wave * 32 + i * 8) * 64);
    }
    __syncthreads();
#pragma unroll
    for (int kk = 0; kk < 2; kk++) {
      short8 af[4], bf[4];
#pragma unroll
      for (int i = 0; i < 4; i++) {
        int row = wm + i * 16 + lrow;
        int pos = ((kk * 4 + quad) ^ (lane & 7)) * 8;
        af[i] = *(const short8*)(As + row * 64 + pos);
      }
#pragma unroll
      for (int j = 0; j < 4; j++) {
        int row = wn + j * 16 + lrow;
        int pos = ((kk * 4 + quad) ^ (lane & 7)) * 8;
        bf[j] = *(const short8*)(Bs + row * 64 + pos);
      }
#pragma unroll
      for (int i = 0; i < 4; i++)
#pragma unroll
        for (int j = 0; j < 4; j++)
          acc[i][j] = __builtin_amdgcn_mfma_f32_16x16x32_bf16(af[i], bf[j], acc[i][j], 0, 0, 0);
    }
  }

  __syncthreads();
  u16* Cs = smem;  // [128][CSTR]

  const int crow0 = quad * 4;
  const int ccol = lane & 15;
#pragma unroll
  for (int i = 0; i < 4; i++)
#pragma unroll
    for (int j = 0; j < 4; j++)
#pragma unroll
      for (int r = 0; r < 4; r++)
        Cs[(wm + i * 16 + crow0 + r) * CSTR + wn + j * 16 + ccol] = f2bf(acc[i][j][r]);
  __syncthreads();

  const int qkv = n0 >> 10;
  const int c0 = (n0 >> 4) & 63;
  const int b = m0 >> 8;
  const int s0 = m0 & 255;
  const int s = t >> 1;
  const int hh = (t & 1) * 8;

#pragma unroll
  for (int g = 0; g < 8; g++) {
    uint4 val = *(const uint4*)(Cs + s * CSTR + g * 16 + hh);
    size_t base = (((size_t)(qkv * 64 + c0 + g) * 32 + b) * 256 + (s0 + s)) * 16 + hh;
    *(uint4*)(QKV + base) = val;
  }
}

// ---------------------------------------------------------------------------
// MFMA attention. Block = (head c, batch b); 4 waves; wave w owns q-rows
// [64w, 64w+64) as 4 q-tiles of 16. Loop over 16 key-tiles of 16:
//   S^T tile = MFMA(A=K-frag, B=Q-frag)           (frag: lane-local loads)
//   P^T = exp(S^T/32, masked) -> bf16, lane-local (C layout == B layout)
//   O^T tile += MFMA(A=V^T-frag, B=P^T)
// l[q] = per-lane fp32 sum of the 4 rounded p's + shfl_xor(16,32).
// Epilogue: O^T -> LDS -> thread t writes out row q=t (64B coalesced) / l.
// ---------------------------------------------------------------------------
__global__ __launch_bounds__(256) void attn_kernel(const u16* __restrict__ QKV,
                                                   const float* __restrict__ mask,
                                                   float* __restrict__ out) {
  __shared__ float m_s[256];
  __shared__ float l_s[256];
  __shared__ float ot[16 * 257];

  const int c = blockIdx.x;
  const int b = blockIdx.y;
  const int t = threadIdx.x;
  const int wave = t >> 6;
  const int lane = t & 63;
  const int col = lane & 15;
  const int quad = lane >> 4;

  const size_t hb = ((size_t)c * 32 + b) * 4096;
  const u16* Qp = QKV + hb;
  const u16* Kp = QKV + QKVSEG + hb;
  const u16* Vp = QKV + 2 * QKVSEG + hb;

  m_s[t] = mask[b * 256 + t];
  __syncthreads();

  const int q0 = wave * 64;

  // Q B-frags: bq[qt][i] = Q[q = q0+qt*16+col][h = quad*4+i]
  short4v bq[4];
#pragma unroll
  for (int qt = 0; qt < 4; qt++)
    bq[qt] = *(const short4v*)(Qp + (q0 + qt * 16 + col) * 16 + quad * 4);

  float mqv[4];
#pragma unroll
  for (int qt = 0; qt < 4; qt++) mqv[qt] = m_s[q0 + qt * 16 + col];

  floatx4 oacc[4] = {};
  float lsum[4] = {0.f, 0.f, 0.f, 0.f};

  for (int kt = 0; kt < 16; kt++) {
    const int kb = kt * 16;
    // K A-frag: ak[i] = K[key=kb+col][h=quad*4+i]
    short4v ak = *(const short4v*)(Kp + (kb + col) * 16 + quad * 4);
    // V^T A-frag: av[i] = V[key=kb+quad*4+i][h=col]
    short4v av;
#pragma unroll
    for (int i = 0; i < 4; i++)
      av[i] = (short)Vp[(kb + quad * 4 + i) * 16 + col];
    float mk[4];
#pragma unroll
    for (int i = 0; i < 4; i++) mk[i] = m_s[kb + quad * 4 + i];

#pragma unroll
    for (int qt = 0; qt < 4; qt++) {
      floatx4 z = {0.f, 0.f, 0.f, 0.f};
      floatx4 st = MFMA16(ak, bq[qt], z);
      short4v p;
      float ps = 0.f;
#pragma unroll
      for (int i = 0; i < 4; i++) {
        float e = __expf(st[i] * 0.03125f);           // / sqrt(1024)
        e = (mqv[qt] * mk[i] > 0.f) ? e : 0.f;
        u16 pb = f2bf(e);
        p[i] = (short)pb;
        ps += bf2f(pb);  // denominator from the SAME rounded p as numerator
      }
      lsum[qt] += ps;
      oacc[qt] = MFMA16(av, p, oacc[qt]);
    }
  }

  // reduce l across the 4 quads; stash O^T fragments to LDS
#pragma unroll
  for (int qt = 0; qt < 4; qt++) {
    float l = lsum[qt];
    l += __shfl_xor(l, 16, 64);
    l += __shfl_xor(l, 32, 64);
    if (quad == 0) l_s[q0 + qt * 16 + col] = l;
#pragma unroll
    for (int r = 0; r < 4; r++)
      ot[(quad * 4 + r) * 257 + q0 + qt * 16 + col] = oacc[qt][r];
  }
  __syncthreads();

  // epilogue: thread t owns q-row t; 64B coalesced store
  float l = l_s[t];
  float* op = out + ((size_t)b * 256 + t) * 1024 + c * 16;
  float o[16];
  if (l > 0.f) {
    float inv = 1.0f / l;
#pragma unroll
    for (int h = 0; h < 16; h++) o[h] = ot[h * 257 + t] * inv;
  } else {
    // fully-masked row: reference softmax of uniform -1e9 -> mean of V
#pragma unroll
    for (int h = 0; h < 16; h++) o[h] = 0.f;
    for (int k = 0; k < 256; k++)
#pragma unroll
      for (int h = 0; h < 16; h++) o[h] += bf2f(Vp[k * 16 + h]);
#pragma unroll
    for (int h = 0; h < 16; h++) o[h] *= (1.0f / 256.0f);
  }
#pragma unroll
  for (int g = 0; g < 4; g++) {
    float4 r;
    r.x = o[g * 4 + 0]; r.y = o[g * 4 + 1]; r.z = o[g * 4 + 2]; r.w = o[g * 4 + 3];
    *(float4*)(op + g * 4) = r;
  }
}

// ---------------------------------------------------------------------------
// Launch
// ---------------------------------------------------------------------------
extern "C" void kernel_launch(void* const* d_in, const int* in_sizes, int n_in,
                              void* d_out, int out_size, void* d_ws, size_t ws_size,
                              hipStream_t stream) {
  const float* x    = (const float*)d_in[0];  // [32,256,1024]
  const float* mask = (const float*)d_in[1];  // [32,256]
  const float* Wq   = (const float*)d_in[2];  // [1024,1024]
  const float* Wk   = (const float*)d_in[3];
  const float* Wv   = (const float*)d_in[4];
  float* out = (float*)d_out;

  u16* XB  = (u16*)d_ws;                    // [8192][1024] bf16
  u16* WB  = XB + (size_t)GM * GK;          // [3072][1024]
  u16* QKV = WB + (size_t)GN * GK;          // [3][64][32][256][16]

  cast_all<<<11264, 256, 0, stream>>>(x, Wq, Wk, Wv, XB, WB);
  gemm_qkv<<<1536, 256, 0, stream>>>(XB, WB, QKV);
  attn_kernel<<<dim3(64, 32), 256, 0, stream>>>(QKV, mask, out);
}

// Round 5
// 187.513 us; speedup vs baseline: 2.5424x; 1.0735x over previous
//
#include <hip/hip_runtime.h>

// ---------------------------------------------------------------------------
// SelfAttentionLayer: out[b,s,c*16+h] = softmax_k( (q.k)/32 masked ) @ v
// R4: attention VALU diet. Q pre-scaled by log2e/32 in GEMM epilogue ->
// p = v_exp(st) raw; bf16 pack via v_perm truncation (numerator==denominator
// so bias cancels); row-sums l via MFMA(ones, p) on the idle matrix pipe;
// all-ones-mask fast path via __syncthreads_and.
// ---------------------------------------------------------------------------

typedef unsigned short u16;
typedef unsigned int u32;
typedef __attribute__((ext_vector_type(8))) short short8;
typedef __attribute__((ext_vector_type(4))) short short4v;
typedef __attribute__((ext_vector_type(4))) float floatx4;

#if __has_builtin(__builtin_amdgcn_mfma_f32_16x16x16bf16_1k)
#define MFMA16(A, B, C) __builtin_amdgcn_mfma_f32_16x16x16bf16_1k(A, B, C, 0, 0, 0)
#elif __has_builtin(__builtin_amdgcn_mfma_f32_16x16x16_bf16)
#define MFMA16(A, B, C) __builtin_amdgcn_mfma_f32_16x16x16_bf16(A, B, C, 0, 0, 0)
#else
__device__ __forceinline__ floatx4 mfma16_asm(short4v a, short4v b, floatx4 c) {
  floatx4 d;
  asm volatile("v_mfma_f32_16x16x16_bf16 %0, %1, %2, %3"
               : "=v"(d) : "v"(a), "v"(b), "v"(c));
  return d;
}
#define MFMA16(A, B, C) mfma16_asm(A, B, C)
#endif

#if __has_builtin(__builtin_amdgcn_exp2f)
#define EXP2(x) __builtin_amdgcn_exp2f(x)
#else
#define EXP2(x) __expf((x) * 0.6931471805599453f)
#endif

// Q pre-scale folded into GEMM epilogue: logits become log2e * (q.k) / 32
#define QSCALE 0.045084220f  // log2(e)/32

__device__ __forceinline__ u16 f2bf(float f) {
  union { float f; u32 u; } x; x.f = f;
  u32 r = x.u + 0x7fffu + ((x.u >> 16) & 1u);  // RNE
  return (u16)(r >> 16);
}
__device__ __forceinline__ float bf2f(u16 u) {
  union { u32 u; float f; } x; x.u = ((u32)u) << 16;
  return x.f;
}

// async global->LDS, 16B per lane; LDS dest = wave-uniform base + lane*16
__device__ __forceinline__ void gload16(const void* g, void* l) {
  typedef __attribute__((address_space(1))) const unsigned int gq;
  typedef __attribute__((address_space(3))) unsigned int lq;
  __builtin_amdgcn_global_load_lds((gq*)(size_t)g, (lq*)(size_t)l, 16, 0, 0);
}

#define GM 8192
#define GN 3072
#define GK 1024
#define CSTR 136
#define QKVSEG (64 * 32 * 4096)

// ---------------------------------------------------------------------------
// Merged cast f32 -> bf16: X (8192 blocks), Wq/Wk/Wv (1024 blocks each)
// ---------------------------------------------------------------------------
__global__ __launch_bounds__(256) void cast_all(const float* __restrict__ x,
                                                const float* __restrict__ wq,
                                                const float* __restrict__ wk,
                                                const float* __restrict__ wv,
                                                u16* __restrict__ XB,
                                                u16* __restrict__ WB) {
  int bid = blockIdx.x;
  const float* src; u16* dst; int off;
  if (bid < 8192)       { src = x;  dst = XB;                 off = bid; }
  else if (bid < 9216)  { src = wq; dst = WB;                 off = bid - 8192; }
  else if (bid < 10240) { src = wk; dst = WB + 1024 * 1024;   off = bid - 9216; }
  else                  { src = wv; dst = WB + 2 * 1024 * 1024; off = bid - 10240; }
  int i = (off * 256 + threadIdx.x) * 4;
  float4 v = *(const float4*)(src + i);
  u32 lo = (u32)f2bf(v.x) | ((u32)f2bf(v.y) << 16);
  u32 hi = (u32)f2bf(v.z) | ((u32)f2bf(v.w) << 16);
  uint2 o; o.x = lo; o.y = hi;
  *(uint2*)(dst + i) = o;
}

// ---------------------------------------------------------------------------
// GEMM: C[m][n] = sum_k A[m][k]*B[n][k]; 128x128 tile, BK=64, XCD swizzle,
// global_load_lds width-16, XOR-swizzled stride-64 LDS.
// Epilogue -> permuted coalesced QKV[qkv][c][b][s][h]; Q scaled by QSCALE.
// ---------------------------------------------------------------------------
__global__ __launch_bounds__(256) void gemm_qkv(const u16* __restrict__ A,
                                                const u16* __restrict__ B,
                                                u16* __restrict__ QKV) {
  __shared__ u16 smem[17408];
  u16* As = smem;
  u16* Bs = smem + 128 * 64;

  const int t = threadIdx.x;
  const int lid = blockIdx.x;
  const int xcd = lid & 7;
  const int slot = lid >> 3;
  const int m0 = (xcd * 8 + (slot & 7)) * 128;
  const int n0 = (slot >> 3) * 128;

  const int wave = t >> 6;
  const int lane = t & 63;
  const int wm = (wave >> 1) * 64;
  const int wn = (wave & 1) * 64;
  const int lrow = lane & 15;
  const int quad = lane >> 4;

  const int r_loc = lane >> 3;
  const int xb = (lane & 7) ^ r_loc;

  floatx4 acc[4][4] = {};

  const size_t arow = (size_t)(m0 + wave * 32 + r_loc) * GK + xb * 8;
  const size_t brow = (size_t)(n0 + wave * 32 + r_loc) * GK + xb * 8;

  for (int k0 = 0; k0 < GK; k0 += 64) {
    __syncthreads();
#pragma unroll
    for (int i = 0; i < 4; i++) {
      gload16(A + arow + (size_t)i * 8 * GK + k0, As + (wave * 32 + i * 8) * 64);
      gload16(B + brow + (size_t)i * 8 * GK + k0, Bs + (wave * 32 + i * 8) * 64);
    }
    __syncthreads();
#pragma unroll
    for (int kk = 0; kk < 2; kk++) {
      short8 af[4], bf[4];
#pragma unroll
      for (int i = 0; i < 4; i++) {
        int row = wm + i * 16 + lrow;
        int pos = ((kk * 4 + quad) ^ (lane & 7)) * 8;
        af[i] = *(const short8*)(As + row * 64 + pos);
      }
#pragma unroll
      for (int j = 0; j < 4; j++) {
        int row = wn + j * 16 + lrow;
        int pos = ((kk * 4 + quad) ^ (lane & 7)) * 8;
        bf[j] = *(const short8*)(Bs + row * 64 + pos);
      }
#pragma unroll
      for (int i = 0; i < 4; i++)
#pragma unroll
        for (int j = 0; j < 4; j++)
          acc[i][j] = __builtin_amdgcn_mfma_f32_16x16x32_bf16(af[i], bf[j], acc[i][j], 0, 0, 0);
    }
  }

  __syncthreads();
  u16* Cs = smem;  // [128][CSTR]

  // Q tiles (n0 < 1024) carry the folded softmax scale
  const float qsc = (n0 < 1024) ? QSCALE : 1.0f;

  const int crow0 = quad * 4;
  const int ccol = lane & 15;
#pragma unroll
  for (int i = 0; i < 4; i++)
#pragma unroll
    for (int j = 0; j < 4; j++)
#pragma unroll
      for (int r = 0; r < 4; r++)
        Cs[(wm + i * 16 + crow0 + r) * CSTR + wn + j * 16 + ccol] = f2bf(acc[i][j][r] * qsc);
  __syncthreads();

  const int qkv = n0 >> 10;
  const int c0 = (n0 >> 4) & 63;
  const int b = m0 >> 8;
  const int s0 = m0 & 255;
  const int s = t >> 1;
  const int hh = (t & 1) * 8;

#pragma unroll
  for (int g = 0; g < 8; g++) {
    uint4 val = *(const uint4*)(Cs + s * CSTR + g * 16 + hh);
    size_t base = (((size_t)(qkv * 64 + c0 + g) * 32 + b) * 256 + (s0 + s)) * 16 + hh;
    *(uint4*)(QKV + base) = val;
  }
}

// ---------------------------------------------------------------------------
// MFMA attention kt-loop: S^T = MFMA(K, Qscaled); p = exp2(st) (trunc-packed
// via v_perm); l via MFMA(ones, p); O^T += MFMA(V^T, p).
// ---------------------------------------------------------------------------
template <bool MASKED>
__device__ __forceinline__ void attn_loop(const u16* __restrict__ Kp,
                                          const u16* __restrict__ Vp,
                                          const short4v* bq, const float* mqv,
                                          const float* m_s,
                                          floatx4* oacc, floatx4* lacc,
                                          int col, int quad) {
  const short4v ones = {(short)0x3F80, (short)0x3F80, (short)0x3F80, (short)0x3F80};
#pragma unroll 2
  for (int kt = 0; kt < 16; kt++) {
    const int kb = kt * 16;
    short4v ak = *(const short4v*)(Kp + (kb + col) * 16 + quad * 4);
    short4v av;
#pragma unroll
    for (int i = 0; i < 4; i++)
      av[i] = (short)Vp[(kb + quad * 4 + i) * 16 + col];
    float mk[4];
    if (MASKED) {
#pragma unroll
      for (int i = 0; i < 4; i++) mk[i] = m_s[kb + quad * 4 + i];
    }
#pragma unroll
    for (int qt = 0; qt < 4; qt++) {
      floatx4 z = {0.f, 0.f, 0.f, 0.f};
      floatx4 st = MFMA16(ak, bq[qt], z);
      float e[4];
#pragma unroll
      for (int i = 0; i < 4; i++) {
        e[i] = EXP2(st[i]);
        if (MASKED) e[i] = (mqv[qt] * mk[i] > 0.f) ? e[i] : 0.f;
      }
      union { u32 u[2]; short4v s; } pk;
      pk.u[0] = __builtin_amdgcn_perm(__float_as_uint(e[1]), __float_as_uint(e[0]), 0x07060302u);
      pk.u[1] = __builtin_amdgcn_perm(__float_as_uint(e[3]), __float_as_uint(e[2]), 0x07060302u);
      lacc[qt] = MFMA16(ones, pk.s, lacc[qt]);
      oacc[qt] = MFMA16(av, pk.s, oacc[qt]);
    }
  }
}

// ---------------------------------------------------------------------------
// Attention. Block = (head c, batch b); wave w owns q-rows [64w,64w+64).
// ---------------------------------------------------------------------------
__global__ __launch_bounds__(256) void attn_kernel(const u16* __restrict__ QKV,
                                                   const float* __restrict__ mask,
                                                   float* __restrict__ out) {
  __shared__ float m_s[256];
  __shared__ float l_s[256];
  __shared__ float ot[16 * 257];

  const int c = blockIdx.x;
  const int b = blockIdx.y;
  const int t = threadIdx.x;
  const int wave = t >> 6;
  const int lane = t & 63;
  const int col = lane & 15;
  const int quad = lane >> 4;

  const size_t hb = ((size_t)c * 32 + b) * 4096;
  const u16* Qp = QKV + hb;
  const u16* Kp = QKV + QKVSEG + hb;
  const u16* Vp = QKV + 2 * QKVSEG + hb;

  float mv = mask[b * 256 + t];
  m_s[t] = mv;
  const int allones = __syncthreads_and(mv > 0.f);

  const int q0 = wave * 64;

  // Q B-frags: bq[qt][i] = Qs[q = q0+qt*16+col][h = quad*4+i]  (pre-scaled)
  short4v bq[4];
#pragma unroll
  for (int qt = 0; qt < 4; qt++)
    bq[qt] = *(const short4v*)(Qp + (q0 + qt * 16 + col) * 16 + quad * 4);

  float mqv[4];
#pragma unroll
  for (int qt = 0; qt < 4; qt++) mqv[qt] = m_s[q0 + qt * 16 + col];

  floatx4 oacc[4] = {};
  floatx4 lacc[4] = {};

  if (allones)
    attn_loop<false>(Kp, Vp, bq, mqv, m_s, oacc, lacc, col, quad);
  else
    attn_loop<true>(Kp, Vp, bq, mqv, m_s, oacc, lacc, col, quad);

  // stash l (all rows of lacc equal the column sum) and O^T fragments
#pragma unroll
  for (int qt = 0; qt < 4; qt++) {
    if (quad == 0) l_s[q0 + qt * 16 + col] = lacc[qt][0];
#pragma unroll
    for (int r = 0; r < 4; r++)
      ot[(quad * 4 + r) * 257 + q0 + qt * 16 + col] = oacc[qt][r];
  }
  __syncthreads();

  // epilogue: thread t owns q-row t; 64B coalesced store
  float l = l_s[t];
  float* op = out + ((size_t)b * 256 + t) * 1024 + c * 16;
  float o[16];
  if (allones || l > 0.f) {
    float inv = 1.0f / l;
#pragma unroll
    for (int h = 0; h < 16; h++) o[h] = ot[h * 257 + t] * inv;
  } else {
    // fully-masked row: reference softmax of uniform -1e9 -> mean of V
#pragma unroll
    for (int h = 0; h < 16; h++) o[h] = 0.f;
    for (int k = 0; k < 256; k++)
#pragma unroll
      for (int h = 0; h < 16; h++) o[h] += bf2f(Vp[k * 16 + h]);
#pragma unroll
    for (int h = 0; h < 16; h++) o[h] *= (1.0f / 256.0f);
  }
#pragma unroll
  for (int g = 0; g < 4; g++) {
    float4 r;
    r.x = o[g * 4 + 0]; r.y = o[g * 4 + 1]; r.z = o[g * 4 + 2]; r.w = o[g * 4 + 3];
    *(float4*)(op + g * 4) = r;
  }
}

// ---------------------------------------------------------------------------
// Launch
// ---------------------------------------------------------------------------
extern "C" void kernel_launch(void* const* d_in, const int* in_sizes, int n_in,
                              void* d_out, int out_size, void* d_ws, size_t ws_size,
                              hipStream_t stream) {
  const float* x    = (const float*)d_in[0];  // [32,256,1024]
  const float* mask = (const float*)d_in[1];  // [32,256]
  const float* Wq   = (const float*)d_in[2];  // [1024,1024]
  const float* Wk   = (const float*)d_in[3];
  const float* Wv   = (const float*)d_in[4];
  float* out = (float*)d_out;

  u16* XB  = (u16*)d_ws;                    // [8192][1024] bf16
  u16* WB  = XB + (size_t)GM * GK;          // [3072][1024]
  u16* QKV = WB + (size_t)GN * GK;          // [3][64][32][256][16]

  cast_all<<<11264, 256, 0, stream>>>(x, Wq, Wk, Wv, XB, WB);
  gemm_qkv<<<1536, 256, 0, stream>>>(XB, WB, QKV);
  attn_kernel<<<dim3(64, 32), 256, 0, stream>>>(QKV, mask, out);
}

// Round 6
// 185.826 us; speedup vs baseline: 2.5655x; 1.0091x over previous
//
#include <hip/hip_runtime.h>

// ---------------------------------------------------------------------------
// SelfAttentionLayer: out[b,s,c*16+h] = softmax_k( (q.k)/32 masked ) @ v
// R5: V stored transposed ([c][b][h][s]) by the GEMM epilogue so the attn
// V^T fragment is one 8B vector load (was 4 scalar 2B loads -> VMEM-bound).
// Attn kt-loop pure + unroll 4 -> loads hoisted, latency covered.
// ---------------------------------------------------------------------------

typedef unsigned short u16;
typedef unsigned int u32;
typedef __attribute__((ext_vector_type(8))) short short8;
typedef __attribute__((ext_vector_type(4))) short short4v;
typedef __attribute__((ext_vector_type(4))) float floatx4;

#if __has_builtin(__builtin_amdgcn_mfma_f32_16x16x16bf16_1k)
#define MFMA16(A, B, C) __builtin_amdgcn_mfma_f32_16x16x16bf16_1k(A, B, C, 0, 0, 0)
#elif __has_builtin(__builtin_amdgcn_mfma_f32_16x16x16_bf16)
#define MFMA16(A, B, C) __builtin_amdgcn_mfma_f32_16x16x16_bf16(A, B, C, 0, 0, 0)
#else
__device__ __forceinline__ floatx4 mfma16_asm(short4v a, short4v b, floatx4 c) {
  floatx4 d;
  asm volatile("v_mfma_f32_16x16x16_bf16 %0, %1, %2, %3"
               : "=v"(d) : "v"(a), "v"(b), "v"(c));
  return d;
}
#define MFMA16(A, B, C) mfma16_asm(A, B, C)
#endif

#if __has_builtin(__builtin_amdgcn_exp2f)
#define EXP2(x) __builtin_amdgcn_exp2f(x)
#else
#define EXP2(x) __expf((x) * 0.6931471805599453f)
#endif

// Q pre-scale folded into GEMM epilogue: logits become log2e * (q.k) / 32
#define QSCALE 0.045084220f  // log2(e)/32

__device__ __forceinline__ u16 f2bf(float f) {
  union { float f; u32 u; } x; x.f = f;
  u32 r = x.u + 0x7fffu + ((x.u >> 16) & 1u);  // RNE
  return (u16)(r >> 16);
}
__device__ __forceinline__ float bf2f(u16 u) {
  union { u32 u; float f; } x; x.u = ((u32)u) << 16;
  return x.f;
}

// async global->LDS, 16B per lane; LDS dest = wave-uniform base + lane*16
__device__ __forceinline__ void gload16(const void* g, void* l) {
  typedef __attribute__((address_space(1))) const unsigned int gq;
  typedef __attribute__((address_space(3))) unsigned int lq;
  __builtin_amdgcn_global_load_lds((gq*)(size_t)g, (lq*)(size_t)l, 16, 0, 0);
}

#define GM 8192
#define GN 3072
#define GK 1024
#define CSTR 136
#define QKVSEG (64 * 32 * 4096)

// ---------------------------------------------------------------------------
// Merged cast f32 -> bf16: X (8192 blocks), Wq/Wk/Wv (1024 blocks each)
// ---------------------------------------------------------------------------
__global__ __launch_bounds__(256) void cast_all(const float* __restrict__ x,
                                                const float* __restrict__ wq,
                                                const float* __restrict__ wk,
                                                const float* __restrict__ wv,
                                                u16* __restrict__ XB,
                                                u16* __restrict__ WB) {
  int bid = blockIdx.x;
  const float* src; u16* dst; int off;
  if (bid < 8192)       { src = x;  dst = XB;                 off = bid; }
  else if (bid < 9216)  { src = wq; dst = WB;                 off = bid - 8192; }
  else if (bid < 10240) { src = wk; dst = WB + 1024 * 1024;   off = bid - 9216; }
  else                  { src = wv; dst = WB + 2 * 1024 * 1024; off = bid - 10240; }
  int i = (off * 256 + threadIdx.x) * 4;
  float4 v = *(const float4*)(src + i);
  u32 lo = (u32)f2bf(v.x) | ((u32)f2bf(v.y) << 16);
  u32 hi = (u32)f2bf(v.z) | ((u32)f2bf(v.w) << 16);
  uint2 o; o.x = lo; o.y = hi;
  *(uint2*)(dst + i) = o;
}

// ---------------------------------------------------------------------------
// GEMM: C[m][n] = sum_k A[m][k]*B[n][k]; 128x128 tile, BK=64, XCD swizzle,
// global_load_lds width-16, XOR-swizzled stride-64 LDS.
// Epilogue: Q tiles scaled by QSCALE -> QKV[0][c][b][s][h];
//           K tiles              -> QKV[1][c][b][s][h];
//           V tiles TRANSPOSED   -> QKV[2][c][b][h][s]  (for attn 8B frags).
// ---------------------------------------------------------------------------
__global__ __launch_bounds__(256) void gemm_qkv(const u16* __restrict__ A,
                                                const u16* __restrict__ B,
                                                u16* __restrict__ QKV) {
  __shared__ u16 smem[17408];
  u16* As = smem;
  u16* Bs = smem + 128 * 64;

  const int t = threadIdx.x;
  const int lid = blockIdx.x;
  const int xcd = lid & 7;
  const int slot = lid >> 3;
  const int m0 = (xcd * 8 + (slot & 7)) * 128;
  const int n0 = (slot >> 3) * 128;

  const int wave = t >> 6;
  const int lane = t & 63;
  const int wm = (wave >> 1) * 64;
  const int wn = (wave & 1) * 64;
  const int lrow = lane & 15;
  const int quad = lane >> 4;

  const int r_loc = lane >> 3;
  const int xb = (lane & 7) ^ r_loc;

  floatx4 acc[4][4] = {};

  const size_t arow = (size_t)(m0 + wave * 32 + r_loc) * GK + xb * 8;
  const size_t brow = (size_t)(n0 + wave * 32 + r_loc) * GK + xb * 8;

  for (int k0 = 0; k0 < GK; k0 += 64) {
    __syncthreads();
#pragma unroll
    for (int i = 0; i < 4; i++) {
      gload16(A + arow + (size_t)i * 8 * GK + k0, As + (wave * 32 + i * 8) * 64);
      gload16(B + brow + (size_t)i * 8 * GK + k0, Bs + (wave * 32 + i * 8) * 64);
    }
    __syncthreads();
#pragma unroll
    for (int kk = 0; kk < 2; kk++) {
      short8 af[4], bf[4];
#pragma unroll
      for (int i = 0; i < 4; i++) {
        int row = wm + i * 16 + lrow;
        int pos = ((kk * 4 + quad) ^ (lane & 7)) * 8;
        af[i] = *(const short8*)(As + row * 64 + pos);
      }
#pragma unroll
      for (int j = 0; j < 4; j++) {
        int row = wn + j * 16 + lrow;
        int pos = ((kk * 4 + quad) ^ (lane & 7)) * 8;
        bf[j] = *(const short8*)(Bs + row * 64 + pos);
      }
#pragma unroll
      for (int i = 0; i < 4; i++)
#pragma unroll
        for (int j = 0; j < 4; j++)
          acc[i][j] = __builtin_amdgcn_mfma_f32_16x16x32_bf16(af[i], bf[j], acc[i][j], 0, 0, 0);
    }
  }

  __syncthreads();
  u16* Cs = smem;  // [128][CSTR]

  const int qkv = n0 >> 10;          // 0=Q 1=K 2=V
  const int c0 = (n0 >> 4) & 63;
  const int b = m0 >> 8;
  const int s0 = m0 & 255;

  const int crow0 = quad * 4;
  const int ccol = lane & 15;

  if (qkv == 2) {
    // V: store acc TRANSPOSED into Cs: Cs[feature][s_local]
#pragma unroll
    for (int i = 0; i < 4; i++)
#pragma unroll
      for (int j = 0; j < 4; j++)
#pragma unroll
        for (int r = 0; r < 4; r++)
          Cs[(wn + j * 16 + ccol) * CSTR + wm + i * 16 + crow0 + r] = f2bf(acc[i][j][r]);
    __syncthreads();

    const int h = t >> 4;          // 0..15
    const int chunk = t & 15;      // 0..15 -> s_local = chunk*8
#pragma unroll
    for (int g = 0; g < 8; g++) {
      uint4 val = *(const uint4*)(Cs + (g * 16 + h) * CSTR + chunk * 8);
      size_t base = (((size_t)(2 * 64 + c0 + g) * 32 + b) * 16 + h) * 256 + s0 + chunk * 8;
      *(uint4*)(QKV + base) = val;
    }
  } else {
    const float qsc = (qkv == 0) ? QSCALE : 1.0f;
#pragma unroll
    for (int i = 0; i < 4; i++)
#pragma unroll
      for (int j = 0; j < 4; j++)
#pragma unroll
        for (int r = 0; r < 4; r++)
          Cs[(wm + i * 16 + crow0 + r) * CSTR + wn + j * 16 + ccol] = f2bf(acc[i][j][r] * qsc);
    __syncthreads();

    const int s = t >> 1;
    const int hh = (t & 1) * 8;
#pragma unroll
    for (int g = 0; g < 8; g++) {
      uint4 val = *(const uint4*)(Cs + s * CSTR + g * 16 + hh);
      size_t base = (((size_t)(qkv * 64 + c0 + g) * 32 + b) * 256 + (s0 + s)) * 16 + hh;
      *(uint4*)(QKV + base) = val;
    }
  }
}

// ---------------------------------------------------------------------------
// MFMA attention kt-loop: S^T = MFMA(K, Qscaled); p = exp2(st) (trunc-packed
// via v_perm); l via MFMA(ones, p); O^T += MFMA(V^T, p).
// Vp is TRANSPOSED [h][s]: av frag = one 8B load. Loop is store-free ->
// unroll 4 lets the compiler keep 8 loads in flight.
// ---------------------------------------------------------------------------
template <bool MASKED>
__device__ __forceinline__ void attn_loop(const u16* __restrict__ Kp,
                                          const u16* __restrict__ Vp,
                                          const short4v* bq, const float* mqv,
                                          const float* m_s,
                                          floatx4* oacc, floatx4* lacc,
                                          int col, int quad) {
  const short4v ones = {(short)0x3F80, (short)0x3F80, (short)0x3F80, (short)0x3F80};
#pragma unroll 4
  for (int kt = 0; kt < 16; kt++) {
    const int kb = kt * 16;
    short4v ak = *(const short4v*)(Kp + (kb + col) * 16 + quad * 4);
    short4v av = *(const short4v*)(Vp + col * 256 + kb + quad * 4);
    float mk[4];
    if (MASKED) {
#pragma unroll
      for (int i = 0; i < 4; i++) mk[i] = m_s[kb + quad * 4 + i];
    }
#pragma unroll
    for (int qt = 0; qt < 4; qt++) {
      floatx4 z = {0.f, 0.f, 0.f, 0.f};
      floatx4 st = MFMA16(ak, bq[qt], z);
      float e[4];
#pragma unroll
      for (int i = 0; i < 4; i++) {
        e[i] = EXP2(st[i]);
        if (MASKED) e[i] = (mqv[qt] * mk[i] > 0.f) ? e[i] : 0.f;
      }
      union { u32 u[2]; short4v s; } pk;
      pk.u[0] = __builtin_amdgcn_perm(__float_as_uint(e[1]), __float_as_uint(e[0]), 0x07060302u);
      pk.u[1] = __builtin_amdgcn_perm(__float_as_uint(e[3]), __float_as_uint(e[2]), 0x07060302u);
      lacc[qt] = MFMA16(ones, pk.s, lacc[qt]);
      oacc[qt] = MFMA16(av, pk.s, oacc[qt]);
    }
  }
}

// ---------------------------------------------------------------------------
// Attention. Block = (head c, batch b); wave w owns q-rows [64w,64w+64).
// ---------------------------------------------------------------------------
__global__ __launch_bounds__(256) void attn_kernel(const u16* __restrict__ QKV,
                                                   const float* __restrict__ mask,
                                                   float* __restrict__ out) {
  __shared__ float m_s[256];
  __shared__ float l_s[256];
  __shared__ float ot[16 * 257];

  const int c = blockIdx.x;
  const int b = blockIdx.y;
  const int t = threadIdx.x;
  const int wave = t >> 6;
  const int lane = t & 63;
  const int col = lane & 15;
  const int quad = lane >> 4;

  const size_t hb = ((size_t)c * 32 + b) * 4096;
  const u16* Qp = QKV + hb;                 // [s][h], pre-scaled
  const u16* Kp = QKV + QKVSEG + hb;        // [s][h]
  const u16* Vp = QKV + 2 * QKVSEG + hb;    // [h][s]  (transposed)

  float mv = mask[b * 256 + t];
  m_s[t] = mv;
  const int allones = __syncthreads_and(mv > 0.f);

  const int q0 = wave * 64;

  // Q B-frags: bq[qt][i] = Qs[q = q0+qt*16+col][h = quad*4+i]
  short4v bq[4];
#pragma unroll
  for (int qt = 0; qt < 4; qt++)
    bq[qt] = *(const short4v*)(Qp + (q0 + qt * 16 + col) * 16 + quad * 4);

  float mqv[4];
#pragma unroll
  for (int qt = 0; qt < 4; qt++) mqv[qt] = m_s[q0 + qt * 16 + col];

  floatx4 oacc[4] = {};
  floatx4 lacc[4] = {};

  if (allones)
    attn_loop<false>(Kp, Vp, bq, mqv, m_s, oacc, lacc, col, quad);
  else
    attn_loop<true>(Kp, Vp, bq, mqv, m_s, oacc, lacc, col, quad);

  // stash l (every row of lacc = column sum) and O^T fragments
#pragma unroll
  for (int qt = 0; qt < 4; qt++) {
    if (quad == 0) l_s[q0 + qt * 16 + col] = lacc[qt][0];
#pragma unroll
    for (int r = 0; r < 4; r++)
      ot[(quad * 4 + r) * 257 + q0 + qt * 16 + col] = oacc[qt][r];
  }
  __syncthreads();

  // epilogue: thread t owns q-row t; 64B coalesced store
  float l = l_s[t];
  float* op = out + ((size_t)b * 256 + t) * 1024 + c * 16;
  float o[16];
  if (allones || l > 0.f) {
    float inv = 1.0f / l;
#pragma unroll
    for (int h = 0; h < 16; h++) o[h] = ot[h * 257 + t] * inv;
  } else {
    // fully-masked row: reference softmax of uniform -1e9 -> mean of V
#pragma unroll
    for (int h = 0; h < 16; h++) o[h] = 0.f;
    for (int k = 0; k < 256; k++)
#pragma unroll
      for (int h = 0; h < 16; h++) o[h] += bf2f(Vp[h * 256 + k]);
#pragma unroll
    for (int h = 0; h < 16; h++) o[h] *= (1.0f / 256.0f);
  }
#pragma unroll
  for (int g = 0; g < 4; g++) {
    float4 r;
    r.x = o[g * 4 + 0]; r.y = o[g * 4 + 1]; r.z = o[g * 4 + 2]; r.w = o[g * 4 + 3];
    *(float4*)(op + g * 4) = r;
  }
}

// ---------------------------------------------------------------------------
// Launch
// ---------------------------------------------------------------------------
extern "C" void kernel_launch(void* const* d_in, const int* in_sizes, int n_in,
                              void* d_out, int out_size, void* d_ws, size_t ws_size,
                              hipStream_t stream) {
  const float* x    = (const float*)d_in[0];  // [32,256,1024]
  const float* mask = (const float*)d_in[1];  // [32,256]
  const float* Wq   = (const float*)d_in[2];  // [1024,1024]
  const float* Wk   = (const float*)d_in[3];
  const float* Wv   = (const float*)d_in[4];
  float* out = (float*)d_out;

  u16* XB  = (u16*)d_ws;                    // [8192][1024] bf16
  u16* WB  = XB + (size_t)GM * GK;          // [3072][1024]
  u16* QKV = WB + (size_t)GN * GK;          // Q,K: [c][b][s][h]; V: [c][b][h][s]

  cast_all<<<11264, 256, 0, stream>>>(x, Wq, Wk, Wv, XB, WB);
  gemm_qkv<<<1536, 256, 0, stream>>>(XB, WB, QKV);
  attn_kernel<<<dim3(64, 32), 256, 0, stream>>>(QKV, mask, out);
}

// Round 7
// 171.719 us; speedup vs baseline: 2.7762x; 1.0821x over previous
//
#include <hip/hip_runtime.h>

// ---------------------------------------------------------------------------
// SelfAttentionLayer: out[b,s,c*16+h] = softmax_k( (q.k)/32 masked ) @ v
// R6: ONE fused kernel. Block = (head c, batch b) computes its own Q,K,V
// (X[b] @ Wslice^T, 25.2 MFLOP, zero redundancy vs the monolithic GEMM),
// stages them through LDS, then runs the R5-verified MFMA attention phase.
// Kills the 100 MB QKV HBM round-trip, one dispatch, and attn's fixed costs.
// ---------------------------------------------------------------------------

typedef unsigned short u16;
typedef unsigned int u32;
typedef __attribute__((ext_vector_type(8))) short short8;
typedef __attribute__((ext_vector_type(4))) short short4v;
typedef __attribute__((ext_vector_type(4))) float floatx4;

#if __has_builtin(__builtin_amdgcn_mfma_f32_16x16x16bf16_1k)
#define MFMA16(A, B, C) __builtin_amdgcn_mfma_f32_16x16x16bf16_1k(A, B, C, 0, 0, 0)
#elif __has_builtin(__builtin_amdgcn_mfma_f32_16x16x16_bf16)
#define MFMA16(A, B, C) __builtin_amdgcn_mfma_f32_16x16x16_bf16(A, B, C, 0, 0, 0)
#else
__device__ __forceinline__ floatx4 mfma16_asm(short4v a, short4v b, floatx4 c) {
  floatx4 d;
  asm volatile("v_mfma_f32_16x16x16_bf16 %0, %1, %2, %3"
               : "=v"(d) : "v"(a), "v"(b), "v"(c));
  return d;
}
#define MFMA16(A, B, C) mfma16_asm(A, B, C)
#endif

#if __has_builtin(__builtin_amdgcn_exp2f)
#define EXP2(x) __builtin_amdgcn_exp2f(x)
#else
#define EXP2(x) __expf((x) * 0.6931471805599453f)
#endif

#define QSCALE 0.045084220f  // log2(e)/32, folded into Q

__device__ __forceinline__ u16 f2bf(float f) {
  union { float f; u32 u; } x; x.f = f;
  u32 r = x.u + 0x7fffu + ((x.u >> 16) & 1u);  // RNE
  return (u16)(r >> 16);
}
__device__ __forceinline__ float bf2f(u16 u) {
  union { u32 u; float f; } x; x.u = ((u32)u) << 16;
  return x.f;
}

// async global->LDS, 16B per lane; LDS dest = wave-uniform base + lane*16
__device__ __forceinline__ void gload16(const void* g, void* l) {
  typedef __attribute__((address_space(1))) const unsigned int gq;
  typedef __attribute__((address_space(3))) unsigned int lq;
  __builtin_amdgcn_global_load_lds((gq*)(size_t)g, (lq*)(size_t)l, 16, 0, 0);
}

#define GK 1024
#define QKS 20   // Qs/Ks row stride (u16): 8B-aligned frags, conflict-free
#define VTS 264  // Vt row stride (u16): 2-way-max banks (free)

// ---------------------------------------------------------------------------
// Merged cast f32 -> bf16: X (8192 blocks), Wq/Wk/Wv (1024 blocks each)
// ---------------------------------------------------------------------------
__global__ __launch_bounds__(256) void cast_all(const float* __restrict__ x,
                                                const float* __restrict__ wq,
                                                const float* __restrict__ wk,
                                                const float* __restrict__ wv,
                                                u16* __restrict__ XB,
                                                u16* __restrict__ WB) {
  int bid = blockIdx.x;
  const float* src; u16* dst; int off;
  if (bid < 8192)       { src = x;  dst = XB;                 off = bid; }
  else if (bid < 9216)  { src = wq; dst = WB;                 off = bid - 8192; }
  else if (bid < 10240) { src = wk; dst = WB + 1024 * 1024;   off = bid - 9216; }
  else                  { src = wv; dst = WB + 2 * 1024 * 1024; off = bid - 10240; }
  int i = (off * 256 + threadIdx.x) * 4;
  float4 v = *(const float4*)(src + i);
  u32 lo = (u32)f2bf(v.x) | ((u32)f2bf(v.y) << 16);
  u32 hi = (u32)f2bf(v.z) | ((u32)f2bf(v.w) << 16);
  uint2 o; o.x = lo; o.y = hi;
  *(uint2*)(dst + i) = o;
}

// ---------------------------------------------------------------------------
// Attn kt-loop (R5-verified math, LDS sources): S^T = MFMA(K, Qscaled);
// p = exp2(st) trunc-packed via v_perm; l via MFMA(ones,p); O^T += MFMA(V^T,p)
// ---------------------------------------------------------------------------
template <bool MASKED>
__device__ __forceinline__ void attn_loop(const u16* __restrict__ Ks,
                                          const u16* __restrict__ Vt,
                                          const short4v* bq, const float* mqv,
                                          const float* m_s,
                                          floatx4* oacc, floatx4* lacc,
                                          int col, int quad) {
  const short4v ones = {(short)0x3F80, (short)0x3F80, (short)0x3F80, (short)0x3F80};
#pragma unroll 4
  for (int kt = 0; kt < 16; kt++) {
    const int kb = kt * 16;
    short4v ak = *(const short4v*)(Ks + (kb + col) * QKS + quad * 4);
    short4v av = *(const short4v*)(Vt + col * VTS + kb + quad * 4);
    float mk[4];
    if (MASKED) {
#pragma unroll
      for (int i = 0; i < 4; i++) mk[i] = m_s[kb + quad * 4 + i];
    }
#pragma unroll
    for (int qt = 0; qt < 4; qt++) {
      floatx4 z = {0.f, 0.f, 0.f, 0.f};
      floatx4 st = MFMA16(ak, bq[qt], z);
      float e[4];
#pragma unroll
      for (int i = 0; i < 4; i++) {
        e[i] = EXP2(st[i]);
        if (MASKED) e[i] = (mqv[qt] * mk[i] > 0.f) ? e[i] : 0.f;
      }
      union { u32 u[2]; short4v s; } pk;
      pk.u[0] = __builtin_amdgcn_perm(__float_as_uint(e[1]), __float_as_uint(e[0]), 0x07060302u);
      pk.u[1] = __builtin_amdgcn_perm(__float_as_uint(e[3]), __float_as_uint(e[2]), 0x07060302u);
      lacc[qt] = MFMA16(ones, pk.s, lacc[qt]);
      oacc[qt] = MFMA16(av, pk.s, oacc[qt]);
    }
  }
}

// ---------------------------------------------------------------------------
// Fused kernel. Block = (c = bid>>5, b = bid&31)  [same-b blocks -> same XCD
// via bid%8 = b%8: X[b] (512 KB) stays L2-resident].
// Phase 1 (GEMM): Q|K|V[256,48] = X[b][256,1024] @ Wslice[48,1024]^T.
//   m97 staging: Xs 256x64 + Ws 48x64 per BK=64 iter, gload16 w16, XOR LDS.
//   4 waves; wave w owns m-strip [64w,64w+64): acc[4 mt][3 nt] 16x16 tiles.
// Phase 2: Q,K (stride-20) + V^T (stride-264) through LDS -> attn_loop.
// LDS: GEMM 38 KB / attn 28.9 KB share smem; +1 KB m_s = 39.9 KB -> 4 blk/CU.
// ---------------------------------------------------------------------------
__global__ __launch_bounds__(256) void fused_qkv_attn(const u16* __restrict__ XB,
                                                      const u16* __restrict__ WB,
                                                      const float* __restrict__ mask,
                                                      float* __restrict__ out) {
  __shared__ u16 smem[19456];   // GEMM: Xs[256*64]@0, Ws[48*64]@16384
                                // attn: Qs@0 (256*20), Ks@5120, Vt@10240 (16*264),
                                //       l_s@14464 (256 f32), ot overlays @0 (16*257 f32)
  __shared__ float m_s[256];

  const int bid = blockIdx.x;
  const int b = bid & 31;
  const int c = bid >> 5;
  const int t = threadIdx.x;
  const int wave = t >> 6;
  const int lane = t & 63;
  const int col = lane & 15;
  const int quad = lane >> 4;

  u16* Xs = smem;
  u16* Ws = smem + 16384;

  float mv = mask[b * 256 + t];
  m_s[t] = mv;
  const int allones = __syncthreads_and(mv > 0.f);

  // ---------------- phase 1: GEMM ----------------
  const int r_loc = lane >> 3;          // 0..7
  const int xb = (lane & 7) ^ r_loc;    // XOR-swizzled source col-block

  floatx4 acc[4][3] = {};  // [mt][nt]: m = wave*64+mt*16, n = nt*16 (0=Q,1=K,2=V)

  const size_t xrow = ((size_t)b * 256 + wave * 64 + r_loc) * GK + xb * 8;
  // W rows for this head: wr in [0,48), grow = (wr>>4)*1024 + c*16 + (wr&15)
  const int wg0 = wave * 2;             // waves 0..2 stage 2 groups of 8 rows
  int wrow0 = 0, wrow1 = 0;
  if (wave < 3) {
    int wr0 = wg0 * 8 + r_loc, wr1 = wr0 + 8;
    wrow0 = (wr0 >> 4) * 1024 + c * 16 + (wr0 & 15);
    wrow1 = (wr1 >> 4) * 1024 + c * 16 + (wr1 & 15);
  }

  for (int k0 = 0; k0 < GK; k0 += 64) {
    __syncthreads();  // prev iter's ds_reads done before DMA overwrites
#pragma unroll
    for (int i = 0; i < 8; i++)
      gload16(XB + xrow + (size_t)i * 8 * GK + k0, Xs + (wave * 64 + i * 8) * 64);
    if (wave < 3) {
      gload16(WB + (size_t)wrow0 * GK + k0 + xb * 8, Ws + (wg0 * 8) * 64);
      gload16(WB + (size_t)wrow1 * GK + k0 + xb * 8, Ws + (wg0 * 8 + 8) * 64);
    }
    __syncthreads();  // tile landed
#pragma unroll
    for (int kk = 0; kk < 2; kk++) {
      const int pos = ((kk * 4 + quad) ^ (lane & 7)) * 8;
      short8 af[4], bf[3];
#pragma unroll
      for (int mt = 0; mt < 4; mt++)
        af[mt] = *(const short8*)(Xs + (wave * 64 + mt * 16 + col) * 64 + pos);
#pragma unroll
      for (int nt = 0; nt < 3; nt++)
        bf[nt] = *(const short8*)(Ws + (nt * 16 + col) * 64 + pos);
#pragma unroll
      for (int mt = 0; mt < 4; mt++)
#pragma unroll
        for (int nt = 0; nt < 3; nt++)
          acc[mt][nt] = __builtin_amdgcn_mfma_f32_16x16x32_bf16(af[mt], bf[nt], acc[mt][nt], 0, 0, 0);
    }
  }

  // ---------------- Q/K/V -> LDS ----------------
  __syncthreads();  // all ds_reads of Xs/Ws done before overlay
  u16* Qs = smem;               // [256][QKS]
  u16* Ks = smem + 5120;        // [256][QKS]
  u16* Vt = smem + 10240;       // [16][VTS]
  float* l_s = (float*)(smem + 14464);

  // C/D layout: row = m-base + quad*4 + r, col(head feature) = lane&15
#pragma unroll
  for (int mt = 0; mt < 4; mt++) {
    const int row = wave * 64 + mt * 16 + quad * 4;
#pragma unroll
    for (int r = 0; r < 4; r++) {
      Qs[(row + r) * QKS + col] = f2bf(acc[mt][0][r] * QSCALE);
      Ks[(row + r) * QKS + col] = f2bf(acc[mt][1][r]);
      Vt[col * VTS + row + r] = f2bf(acc[mt][2][r]);
    }
  }
  __syncthreads();

  // ---------------- phase 2: attention ----------------
  const int q0 = wave * 64;

  short4v bq[4];
#pragma unroll
  for (int qt = 0; qt < 4; qt++)
    bq[qt] = *(const short4v*)(Qs + (q0 + qt * 16 + col) * QKS + quad * 4);

  float mqv[4];
#pragma unroll
  for (int qt = 0; qt < 4; qt++) mqv[qt] = m_s[q0 + qt * 16 + col];

  floatx4 oacc[4] = {};
  floatx4 lacc[4] = {};

  if (allones)
    attn_loop<false>(Ks, Vt, bq, mqv, m_s, oacc, lacc, col, quad);
  else
    attn_loop<true>(Ks, Vt, bq, mqv, m_s, oacc, lacc, col, quad);

  __syncthreads();  // all waves out of attn_loop before ot overlays Qs/Ks
  float* ot = (float*)smem;  // [16][257] = 16.4 KB, inside Qs+Ks (20.5 KB)

#pragma unroll
  for (int qt = 0; qt < 4; qt++) {
    if (quad == 0) l_s[q0 + qt * 16 + col] = lacc[qt][0];
#pragma unroll
    for (int r = 0; r < 4; r++)
      ot[(quad * 4 + r) * 257 + q0 + qt * 16 + col] = oacc[qt][r];
  }
  __syncthreads();

  // epilogue: thread t owns q-row t; 64B coalesced f32 store
  float l = l_s[t];
  float* op = out + ((size_t)b * 256 + t) * 1024 + c * 16;
  float o[16];
  if (allones || l > 0.f) {
    float inv = 1.0f / l;
#pragma unroll
    for (int h = 0; h < 16; h++) o[h] = ot[h * 257 + t] * inv;
  } else {
    // fully-masked row: reference softmax of uniform -1e9 -> mean of V
#pragma unroll
    for (int h = 0; h < 16; h++) o[h] = 0.f;
    for (int k = 0; k < 256; k++)
#pragma unroll
      for (int h = 0; h < 16; h++) o[h] += bf2f(Vt[h * VTS + k]);
#pragma unroll
    for (int h = 0; h < 16; h++) o[h] *= (1.0f / 256.0f);
  }
#pragma unroll
  for (int g = 0; g < 4; g++) {
    float4 r;
    r.x = o[g * 4 + 0]; r.y = o[g * 4 + 1]; r.z = o[g * 4 + 2]; r.w = o[g * 4 + 3];
    *(float4*)(op + g * 4) = r;
  }
}

// ---------------------------------------------------------------------------
// Launch
// ---------------------------------------------------------------------------
extern "C" void kernel_launch(void* const* d_in, const int* in_sizes, int n_in,
                              void* d_out, int out_size, void* d_ws, size_t ws_size,
                              hipStream_t stream) {
  const float* x    = (const float*)d_in[0];  // [32,256,1024]
  const float* mask = (const float*)d_in[1];  // [32,256]
  const float* Wq   = (const float*)d_in[2];  // [1024,1024]
  const float* Wk   = (const float*)d_in[3];
  const float* Wv   = (const float*)d_in[4];
  float* out = (float*)d_out;

  u16* XB = (u16*)d_ws;                       // [8192][1024] bf16
  u16* WB = XB + (size_t)8192 * 1024;         // [3072][1024] (Wq,Wk,Wv stacked)

  cast_all<<<11264, 256, 0, stream>>>(x, Wq, Wk, Wv, XB, WB);
  fused_qkv_attn<<<2048, 256, 0, stream>>>(XB, WB, mask, out);
}